// Round 3
// baseline (67.476 us; speedup 1.0000x reference)
//
#include <hip/hip_runtime.h>
#include <hip/hip_bf16.h>
#include <math.h>

// ---------------------------------------------------------------------------
// NTXentLoss fused, symmetric triangle + R1-style pipelined GEMM.
// loss = mean(lse(logits) - picked), logits = G G^T, G = sqrt(2)*f/||f||.
// Lower-triangle tile-pairs only; tile (rb,cb) contributes exp-row-sums to
// panel rb (slot ch) and exp-col-sums to panel cb (slots 8+2rb+wr).
// Every partial slot has a unique writer -> deterministic, no atomics; the
// finalizer sums exactly the written slots -> no zero-init needed.
// picked[i<B] = logits[i,i] = 2.0 exactly (labels = cat(arange,arange));
// picked[i>=B] = cross-pair cosine*2, computed in fp32 at normalize time.
// ---------------------------------------------------------------------------

#define B_ROWS 4096
#define D_DIM  256
#define N_ROWS 8192
#define NPANEL 64            // 8192 / 128 row panels

typedef __attribute__((ext_vector_type(8))) short short8;
typedef __attribute__((ext_vector_type(4))) float f32x4;

// ---------------- kernel 1: normalize (fp32->bf16) + picked ----------------
// block = 256 thr = 4 waves; pair p per 2 waves (w&1 -> f1/f2 source row).
__global__ __launch_bounds__(256) void nt_norm_picked(
    const float* __restrict__ f1, const float* __restrict__ f2,
    unsigned short* __restrict__ G, float* __restrict__ picked_cross) {
  __shared__ float4 vbuf[2][64];
  __shared__ float ssbuf[2];
  const int tid = threadIdx.x, lane = tid & 63, w = tid >> 6;
  const int pl = w >> 1, src = w & 1;
  const int p = blockIdx.x * 2 + pl;               // pair index 0..B-1
  const float* rowp = (src == 0 ? f1 : f2) + (size_t)p * D_DIM;
  float4 v = reinterpret_cast<const float4*>(rowp)[lane];
  float ss = v.x * v.x + v.y * v.y + v.z * v.z + v.w * v.w;
#pragma unroll
  for (int m = 1; m < 64; m <<= 1) ss += __shfl_xor(ss, m, 64);
  const float scale = 1.41421356237309515f * rsqrtf(fmaxf(ss, 1e-30f));
  union { ushort4 u; __hip_bfloat16 h[4]; } pk;
  pk.h[0] = __float2bfloat16(v.x * scale);
  pk.h[1] = __float2bfloat16(v.y * scale);
  pk.h[2] = __float2bfloat16(v.z * scale);
  pk.h[3] = __float2bfloat16(v.w * scale);
  const int grow = p + src * B_ROWS;
  reinterpret_cast<ushort4*>(G + (size_t)grow * D_DIM)[lane] = pk.u;
  if (src == 0) { vbuf[pl][lane] = v; if (lane == 0) ssbuf[pl] = ss; }
  __syncthreads();
  if (src == 1) {
    float4 u = vbuf[pl][lane];
    float d = v.x * u.x + v.y * u.y + v.z * u.z + v.w * u.w;
#pragma unroll
    for (int m = 1; m < 64; m <<= 1) d += __shfl_xor(d, m, 64);
    if (lane == 0)
      picked_cross[p] = 2.0f * d * rsqrtf(ss) * rsqrtf(ssbuf[pl]);
  }
}

// ------------- staging helper: contiguous global -> LDS, swizzled ----------
// LDS[o] = G[base + swz(o)], swz(o) = o ^ (((o>>9)&7)<<4)  (row stride 512 B).
__device__ __forceinline__ void stage_lds(const char* gsrc_base, char* lds_base,
                                          int rounds, int tid) {
  const int lane = tid & 63, wid = tid >> 6;
  for (int r = 0; r < rounds; ++r) {
    const int o  = r * 4096 + wid * 1024 + lane * 16;
    const int so = o ^ (((o >> 9) & 7) << 4);
    __builtin_amdgcn_global_load_lds(
        (const __attribute__((address_space(1))) void*)(gsrc_base + so),
        (__attribute__((address_space(3))) void*)(lds_base + r * 4096 + wid * 1024),
        16, 0, 0);
  }
}

// -------- kernel 2: triangular pipelined GEMM + fused exp row/col sums -----
// grid 512 = 64 rb (heavy-first) x 8 ch; block 256 (4 waves, 2x2).
// A panel (rb, 128 rows) -> registers; B subtiles (64 cols = 32 KB)
// double-buffered in 64 KB LDS with global_load_lds prefetch.
__global__ __launch_bounds__(256, 2) void nt_gemm_tri(
    const unsigned short* __restrict__ G,
    float* __restrict__ partial)   // [8 + 128][N_ROWS]
{
  const int bid = blockIdx.x;
  const int rb  = 63 - (bid >> 3);   // heavy blocks first in dispatch order
  const int ch  = bid & 7;
  const int cb0 = ch << 3;
  if (cb0 > rb) return;              // empty block (upper triangle)
  const int nsub = (rb + 1 - cb0 < 8 ? rb + 1 - cb0 : 8) << 1;  // 64-col subtiles

  const int tid  = threadIdx.x;
  const int lane = tid & 63;
  const int wid  = tid >> 6;
  const int wr   = wid >> 1;         // row half (64 rows)
  const int wc   = wid & 1;          // col half (32 cols of 64-col subtile)

  __shared__ short8 lds8[4096];      // 64 KB
  char* ldsb = reinterpret_cast<char*>(lds8);
  const char* gb = reinterpret_cast<const char*>(G);

  // ---- stage A panel (rows rb*128..+128, 64 KB) -> registers ----
  stage_lds(gb + (size_t)rb * 65536, ldsb, 16, tid);
  __syncthreads();
  short8 afrag[4][8];
  {
    const int r0 = wr * 64;
#pragma unroll
    for (int m = 0; m < 4; ++m) {
      const int row = r0 + m * 16 + (lane & 15);
      const int sw  = (row & 7) << 4;
#pragma unroll
      for (int ks = 0; ks < 8; ++ks) {
        const int off = (row * 512 + ks * 64 + ((lane >> 4) << 4)) ^ sw;
        afrag[m][ks] = *reinterpret_cast<const short8*>(ldsb + off);
      }
    }
  }
  __syncthreads();                   // A reads done before B staging

  float rs[16];
#pragma unroll
  for (int i = 0; i < 16; ++i) rs[i] = 0.f;

  // prologue: stage B subtile 0 into buffer 0
  stage_lds(gb + (size_t)cb0 * 65536, ldsb, 8, tid);
  __syncthreads();

  for (int s = 0; s < nsub; ++s) {
    if (s + 1 < nsub)                // prefetch next subtile into other buffer
      stage_lds(gb + (size_t)cb0 * 65536 + (size_t)(s + 1) * 32768,
                ldsb + ((s + 1) & 1) * 32768, 8, tid);

    const char* bbuf = ldsb + (s & 1) * 32768;
    f32x4 acc[4][2] = {};
#pragma unroll
    for (int ks = 0; ks < 8; ++ks) {
      short8 bfrag[2];
#pragma unroll
      for (int n = 0; n < 2; ++n) {
        const int brow = wc * 32 + n * 16 + (lane & 15);
        const int off  = (brow * 512 + ks * 64 + ((lane >> 4) << 4)) ^ ((brow & 7) << 4);
        bfrag[n] = *reinterpret_cast<const short8*>(bbuf + off);
      }
#pragma unroll
      for (int m = 0; m < 4; ++m)
#pragma unroll
        for (int n = 0; n < 2; ++n)
          acc[m][n] = __builtin_amdgcn_mfma_f32_16x16x32_bf16(
              afrag[m][ks], bfrag[n], acc[m][n], 0, 0, 0);
    }
    // exp: rows rs accumulate across subtiles; cols cs reduced+stored now
    float cs0 = 0.f, cs1 = 0.f;
#pragma unroll
    for (int m = 0; m < 4; ++m)
#pragma unroll
      for (int j = 0; j < 4; ++j) {
        const float e0 = __expf(acc[m][0][j]);
        const float e1 = __expf(acc[m][1][j]);
        rs[m * 4 + j] += e0 + e1;
        cs0 += e0; cs1 += e1;
      }
    const int cb = cb0 + (s >> 1);
    if (cb != rb) {                  // diagonal tile: row sums only
      cs0 += __shfl_xor(cs0, 16, 64); cs0 += __shfl_xor(cs0, 32, 64);
      cs1 += __shfl_xor(cs1, 16, 64); cs1 += __shfl_xor(cs1, 32, 64);
      if (lane < 16) {
        float* dst = partial + (size_t)(8 + 2 * rb + wr) * N_ROWS
                   + cb0 * 128 + s * 64 + wc * 32 + lane;
        dst[0]  = cs0;               // n=0 cols
        dst[16] = cs1;               // n=1 cols
      }
    }
    __syncthreads();                 // subtile s+1 resident; buf s reads done
  }

  // ---- row-sum reduce across the 16 col-lanes, then across wc via LDS ----
#pragma unroll
  for (int i = 0; i < 16; ++i) {
    float v = rs[i];
    v += __shfl_xor(v, 1, 64);
    v += __shfl_xor(v, 2, 64);
    v += __shfl_xor(v, 4, 64);
    v += __shfl_xor(v, 8, 64);
    rs[i] = v;
  }
  __syncthreads();                   // LDS free for reduction
  float* redr = reinterpret_cast<float*>(ldsb);   // [2(wc)][128]
  if ((lane & 15) == 0) {
    const int g = lane >> 4;
#pragma unroll
    for (int i = 0; i < 16; ++i)
      redr[wc * 128 + wr * 64 + (i >> 2) * 16 + g * 4 + (i & 3)] = rs[i];
  }
  __syncthreads();
  if (tid < 128)
    partial[(size_t)ch * N_ROWS + (size_t)rb * 128 + tid] =
        redr[tid] + redr[128 + tid];
}

// ------------- kernel 3a: per-panel loss partials --------------------------
// For panel p, written slots: ch = 0..(p>>3) (row sums) and 8+2rb+{0,1} for
// rb = p+1..63 (col sums). Sum exactly those -> no zero-init of partial.
__global__ __launch_bounds__(128) void nt_finalize1(
    const float* __restrict__ partial, const float* __restrict__ picked_cross,
    float* __restrict__ loss_part) {
  const int p = blockIdx.x, tid = threadIdx.x;
  const int r = p * 128 + tid;
  float s = 0.f;
  const int chmax = p >> 3;
  for (int ch = 0; ch <= chmax; ++ch) s += partial[(size_t)ch * N_ROWS + r];
  for (int rb = p + 1; rb < NPANEL; ++rb) {
    s += partial[(size_t)(8 + 2 * rb) * N_ROWS + r];
    s += partial[(size_t)(9 + 2 * rb) * N_ROWS + r];
  }
  const float pick = (r < B_ROWS) ? 2.0f : picked_cross[r - B_ROWS];
  float local = __logf(s) - pick;
#pragma unroll
  for (int m = 1; m < 64; m <<= 1) local += __shfl_xor(local, m, 64);
  __shared__ float red[2];
  if ((tid & 63) == 0) red[tid >> 6] = local;
  __syncthreads();
  if (tid == 0) loss_part[p] = red[0] + red[1];
}

// ------------- kernel 3b: final mean ---------------------------------------
__global__ __launch_bounds__(64) void nt_finalize2(
    const float* __restrict__ loss_part, float* __restrict__ out) {
  const int tid = threadIdx.x;
  float v = loss_part[tid];
#pragma unroll
  for (int m = 1; m < 64; m <<= 1) v += __shfl_xor(v, m, 64);
  if (tid == 0) out[0] = v / (float)N_ROWS;
}

// ---------------------------------------------------------------------------
extern "C" void kernel_launch(void* const* d_in, const int* in_sizes, int n_in,
                              void* d_out, int out_size, void* d_ws, size_t ws_size,
                              hipStream_t stream) {
  const float* f1 = (const float*)d_in[0];
  const float* f2 = (const float*)d_in[1];
  float* out = (float*)d_out;

  char* ws = (char*)d_ws;
  unsigned short* G    = (unsigned short*)ws;                        // 4 MB
  float* partial       = (float*)(ws + (size_t)4 * 1024 * 1024);     // 136*32KB = 4.25 MB
  float* picked_cross  = (float*)(ws + (size_t)9 * 1024 * 1024);     // 16 KB
  float* loss_part     = (float*)(ws + (size_t)9 * 1024 * 1024 + 64 * 1024); // 256 B

  hipLaunchKernelGGL(nt_norm_picked, dim3(B_ROWS / 2), dim3(256), 0, stream,
                     f1, f2, G, picked_cross);
  hipLaunchKernelGGL(nt_gemm_tri, dim3(NPANEL * 8), dim3(256), 0, stream,
                     G, partial);
  hipLaunchKernelGGL(nt_finalize1, dim3(NPANEL), dim3(128), 0, stream,
                     partial, picked_cross, loss_part);
  hipLaunchKernelGGL(nt_finalize2, dim3(1), dim3(64), 0, stream,
                     loss_part, out);
}